// Round 16
// baseline (222.993 us; speedup 1.0000x reference)
//
#include <hip/hip_runtime.h>
#include <hip/hip_cooperative_groups.h>

namespace cg = cooperative_groups;

#define N_NODES  100000
#define N_EDGES  1600000
#define N_AGENTS 50000
#define D_EDGE   48
#define D_IN     208
#define D_HID    256
#define D_OUT    64

#define K1_PAD   224            // D_IN padded to 7*32 for MFMA K-steps
#define F_STRIDE 248            // feat LDS row stride (u16)
#define H_STRIDE 264            // hbuf LDS row stride (u16)
#define AGB      64             // agents per MLP block

#define BCAP     64             // per-node bucket capacity (P(deg>64) ~ 1e-20)
#define ZERO_INT4   50016       // cnt slot + mask slot: 800,256 bytes / 16
#define COOP_BLOCKS 512         // 2 blocks/CU -> trivially co-resident

typedef __attribute__((ext_vector_type(8))) short short8;   // 8 bf16 = 4 VGPRs
typedef __attribute__((ext_vector_type(4))) float f32x4;

static __device__ __forceinline__ unsigned short f2bf(float f) {
    unsigned u = __float_as_uint(f);
    u += 0x7FFFu + ((u >> 16) & 1u);    // round-to-nearest-even
    return (unsigned short)(u >> 16);
}

// ---------------------------------------------------------------------------
// Cooperative chain: {weight-pack + zero} -> sync -> {mask} -> sync -> {place}.
// Replaces 3 dispatches (prep0, mask, place) with one, killing ~2 dispatch
// gaps (~7-8us each, measured r8->r10->r14). All phase bodies byte-equivalent
// to round 14's kernels.
// ---------------------------------------------------------------------------
__global__ __launch_bounds__(256, 2)
void chain_coop(const float* __restrict__ W1, const float* __restrict__ W2,
                unsigned short* __restrict__ w1p, unsigned short* __restrict__ w2p,
                int4* __restrict__ zbase,
                const int* __restrict__ node_idx, int* __restrict__ mask,
                const int* __restrict__ row, int* __restrict__ cnt,
                int* __restrict__ bucket) {
    cg::grid_group grid = cg::this_grid();
    const int gtid  = blockIdx.x * 256 + threadIdx.x;     // < 131,072
    const int nthr  = COOP_BLOCKS * 256;

    // ---- phase 0: pack W1/W2 fragments + zero cnt/mask ----
    if (gtid < 16 * 7 * 64) {                    // W1 fragments (9216 total w/ W2)
        int t = gtid;
        int lane = t & 63;
        int ks   = (t >> 6) % 7;
        int tile = t / (7 * 64);
        int n = tile * 16 + (lane & 15);
        int kb = ks * 32 + (lane >> 4) * 8;
        unsigned short v[8];
        #pragma unroll
        for (int j = 0; j < 8; ++j) {
            int k = kb + j;
            v[j] = (k < D_IN) ? f2bf(W1[k * D_HID + n]) : (unsigned short)0;
        }
        #pragma unroll
        for (int j = 0; j < 8; ++j) w1p[t * 8 + j] = v[j];
    } else if (gtid < 16 * 7 * 64 + 4 * 8 * 64) {
        int u = gtid - 16 * 7 * 64;
        int lane = u & 63;
        int ks   = (u >> 6) & 7;
        int tile = u / (8 * 64);
        int o = tile * 16 + (lane & 15);
        int kb = ks * 32 + (lane >> 4) * 8;
        #pragma unroll
        for (int j = 0; j < 8; ++j)
            w2p[u * 8 + j] = f2bf(W2[(kb + j) * D_OUT + o]);
    }
    for (int i = gtid; i < ZERO_INT4; i += nthr) {
        int4 zz; zz.x = 0; zz.y = 0; zz.z = 0; zz.w = 0;
        zbase[i] = zz;
    }
    grid.sync();

    // ---- phase 1: mark nodes referenced by agents ----
    if (gtid < N_AGENTS) mask[node_idx[gtid]] = 1;
    grid.sync();

    // ---- phase 2: masked bucket placement (grid-stride) ----
    for (int e = gtid; e < N_EDGES; e += nthr) {
        int r = row[e];
        if (!mask[r]) continue;
        int pos = atomicAdd(&cnt[r], 1);
        if ((unsigned)pos < (unsigned)BCAP) bucket[r * BCAP + pos] = e;
    }
}

// ---------------------------------------------------------------------------
// MFMA MLP with fused edge aggregation — byte-identical to round 14.
// ---------------------------------------------------------------------------
__global__ __launch_bounds__(256)
void mlp_mfma(const float* __restrict__ x,
              const float* __restrict__ x_lstm,
              const float* __restrict__ z,
              const float* __restrict__ edge_attr,
              const int* __restrict__ cnt,
              const int* __restrict__ bucket,
              const int* __restrict__ node_idx,
              const unsigned short* __restrict__ w1p,
              const float* __restrict__ b1,
              const unsigned short* __restrict__ w2p,
              const float* __restrict__ b2,
              float* __restrict__ out) {
    __shared__ unsigned short feat[AGB][F_STRIDE];   // 31,744 B
    __shared__ unsigned short hbuf[AGB][H_STRIDE];   // 33,792 B

    const int tid  = threadIdx.x;
    const int w    = tid >> 6;
    const int lane = tid & 63;
    const int ag0  = blockIdx.x * AGB;

    // ---- gather: 4 threads/agent; x/lstm/z float4 loads + edge summation ----
    {
        const int a   = tid >> 2;
        const int sub = tid & 3;
        const int ag  = ag0 + a;
        unsigned short* frow = &feat[a][0];
        if (ag < N_AGENTS) {
            const int nid = node_idx[ag];
            #pragma unroll
            for (int i = 0; i < 4; ++i) {            // x
                int q = i * 4 + sub;
                float4 v = *reinterpret_cast<const float4*>(&x[(long long)nid * 64 + q * 4]);
                ushort4 b; b.x = f2bf(v.x); b.y = f2bf(v.y); b.z = f2bf(v.z); b.w = f2bf(v.w);
                *reinterpret_cast<ushort4*>(&frow[q * 4]) = b;
            }
            #pragma unroll
            for (int i = 0; i < 4; ++i) {            // x_lstm
                int q = i * 4 + sub;
                float4 v = *reinterpret_cast<const float4*>(&x_lstm[(long long)ag * 64 + q * 4]);
                ushort4 b; b.x = f2bf(v.x); b.y = f2bf(v.y); b.z = f2bf(v.z); b.w = f2bf(v.w);
                *reinterpret_cast<ushort4*>(&frow[64 + q * 4]) = b;
            }
            #pragma unroll
            for (int i = 0; i < 2; ++i) {            // z
                int q = i * 4 + sub;
                float4 v = *reinterpret_cast<const float4*>(&z[(long long)ag * 32 + q * 4]);
                ushort4 b; b.x = f2bf(v.x); b.y = f2bf(v.y); b.z = f2bf(v.z); b.w = f2bf(v.w);
                *reinterpret_cast<ushort4*>(&frow[128 + q * 4]) = b;
            }
            // edge aggregation: channels [sub*12, sub*12+12)
            {
                int deg = cnt[nid];
                if (deg > BCAP) deg = BCAP;
                const int* brow = &bucket[nid * BCAP];
                const float* ea = edge_attr + sub * 12;
                float acc[12];
                #pragma unroll
                for (int q = 0; q < 12; ++q) acc[q] = 0.f;
                int j = 0;
                for (; j + 2 <= deg; j += 2) {
                    const float* p0 = ea + (long long)brow[j] * D_EDGE;
                    const float* p1 = ea + (long long)brow[j + 1] * D_EDGE;
                    float4 a0 = *reinterpret_cast<const float4*>(p0);
                    float4 a1 = *reinterpret_cast<const float4*>(p0 + 4);
                    float4 a2 = *reinterpret_cast<const float4*>(p0 + 8);
                    float4 c0 = *reinterpret_cast<const float4*>(p1);
                    float4 c1 = *reinterpret_cast<const float4*>(p1 + 4);
                    float4 c2 = *reinterpret_cast<const float4*>(p1 + 8);
                    acc[0] += a0.x; acc[1] += a0.y; acc[2]  += a0.z; acc[3]  += a0.w;
                    acc[4] += a1.x; acc[5] += a1.y; acc[6]  += a1.z; acc[7]  += a1.w;
                    acc[8] += a2.x; acc[9] += a2.y; acc[10] += a2.z; acc[11] += a2.w;
                    acc[0] += c0.x; acc[1] += c0.y; acc[2]  += c0.z; acc[3]  += c0.w;
                    acc[4] += c1.x; acc[5] += c1.y; acc[6]  += c1.z; acc[7]  += c1.w;
                    acc[8] += c2.x; acc[9] += c2.y; acc[10] += c2.z; acc[11] += c2.w;
                }
                if (j < deg) {
                    const float* p0 = ea + (long long)brow[j] * D_EDGE;
                    float4 a0 = *reinterpret_cast<const float4*>(p0);
                    float4 a1 = *reinterpret_cast<const float4*>(p0 + 4);
                    float4 a2 = *reinterpret_cast<const float4*>(p0 + 8);
                    acc[0] += a0.x; acc[1] += a0.y; acc[2]  += a0.z; acc[3]  += a0.w;
                    acc[4] += a1.x; acc[5] += a1.y; acc[6]  += a1.z; acc[7]  += a1.w;
                    acc[8] += a2.x; acc[9] += a2.y; acc[10] += a2.z; acc[11] += a2.w;
                }
                ushort4 u0, u1, u2;
                u0.x = f2bf(acc[0]); u0.y = f2bf(acc[1]); u0.z = f2bf(acc[2]);  u0.w = f2bf(acc[3]);
                u1.x = f2bf(acc[4]); u1.y = f2bf(acc[5]); u1.z = f2bf(acc[6]);  u1.w = f2bf(acc[7]);
                u2.x = f2bf(acc[8]); u2.y = f2bf(acc[9]); u2.z = f2bf(acc[10]); u2.w = f2bf(acc[11]);
                *reinterpret_cast<ushort4*>(&frow[160 + sub * 12])     = u0;
                *reinterpret_cast<ushort4*>(&frow[160 + sub * 12 + 4]) = u1;
                *reinterpret_cast<ushort4*>(&frow[160 + sub * 12 + 8]) = u2;
            }
            ushort4 zz; zz.x = 0; zz.y = 0; zz.z = 0; zz.w = 0;
            *reinterpret_cast<ushort4*>(&frow[208 + sub * 4]) = zz;   // pad
        } else {
            ushort4 zz; zz.x = 0; zz.y = 0; zz.z = 0; zz.w = 0;
            #pragma unroll
            for (int i = 0; i < 14; ++i)
                *reinterpret_cast<ushort4*>(&frow[(i * 4 + sub) * 4]) = zz;
        }
    }
    __syncthreads();

    const int m16 = lane & 15;
    const int g   = lane >> 4;

    const short8* w1v = reinterpret_cast<const short8*>(w1p);
    const short8* w2v = reinterpret_cast<const short8*>(w2p);

    // ---- layer 1: 2 chunks x {2 M-tiles, 4 N-tiles x 7 K} ----
    for (int mc = 0; mc < 2; ++mc) {
        const int a0 = mc * 32 + m16;
        const int a1 = mc * 32 + 16 + m16;
        short8 bf0[7], bf1[7];
        #pragma unroll
        for (int ks = 0; ks < 7; ++ks) {
            bf0[ks] = *reinterpret_cast<const short8*>(&feat[a0][ks * 32 + g * 8]);
            bf1[ks] = *reinterpret_cast<const short8*>(&feat[a1][ks * 32 + g * 8]);
        }
        #pragma unroll
        for (int nt = 0; nt < 4; ++nt) {
            const int gt = w * 4 + nt;
            f32x4 c0 = {0.f, 0.f, 0.f, 0.f};
            f32x4 c1 = {0.f, 0.f, 0.f, 0.f};
            #pragma unroll
            for (int ks = 0; ks < 7; ++ks) {
                short8 wf = w1v[(gt * 7 + ks) * 64 + lane];
                c0 = __builtin_amdgcn_mfma_f32_16x16x32_bf16(wf, bf0[ks], c0, 0, 0, 0);
                c1 = __builtin_amdgcn_mfma_f32_16x16x32_bf16(wf, bf1[ks], c1, 0, 0, 0);
            }
            float4 bb = *reinterpret_cast<const float4*>(&b1[gt * 16 + g * 4]);
            ushort4 h0, h1;
            h0.x = f2bf(fmaxf(c0[0] + bb.x, 0.f));
            h0.y = f2bf(fmaxf(c0[1] + bb.y, 0.f));
            h0.z = f2bf(fmaxf(c0[2] + bb.z, 0.f));
            h0.w = f2bf(fmaxf(c0[3] + bb.w, 0.f));
            h1.x = f2bf(fmaxf(c1[0] + bb.x, 0.f));
            h1.y = f2bf(fmaxf(c1[1] + bb.y, 0.f));
            h1.z = f2bf(fmaxf(c1[2] + bb.z, 0.f));
            h1.w = f2bf(fmaxf(c1[3] + bb.w, 0.f));
            *reinterpret_cast<ushort4*>(&hbuf[a0][gt * 16 + g * 4]) = h0;
            *reinterpret_cast<ushort4*>(&hbuf[a1][gt * 16 + g * 4]) = h1;
        }
    }
    __syncthreads();

    // ---- layer 2: wave w owns units [w*16, w*16+16); 4 M-tiles ----
    {
        short8 w2f[8];
        #pragma unroll
        for (int ks = 0; ks < 8; ++ks)
            w2f[ks] = w2v[(w * 8 + ks) * 64 + lane];

        float4 bo = *reinterpret_cast<const float4*>(&b2[w * 16 + g * 4]);
        #pragma unroll
        for (int mt = 0; mt < 4; ++mt) {
            const int a = mt * 16 + m16;
            short8 hf[8];
            #pragma unroll
            for (int ks = 0; ks < 8; ++ks)
                hf[ks] = *reinterpret_cast<const short8*>(&hbuf[a][ks * 32 + g * 8]);
            f32x4 acc = {0.f, 0.f, 0.f, 0.f};
            #pragma unroll
            for (int ks = 0; ks < 8; ++ks)
                acc = __builtin_amdgcn_mfma_f32_16x16x32_bf16(w2f[ks], hf[ks], acc, 0, 0, 0);
            const int ag = ag0 + a;
            if (ag < N_AGENTS) {
                float4 o4;
                o4.x = acc[0] + bo.x;
                o4.y = acc[1] + bo.y;
                o4.z = acc[2] + bo.z;
                o4.w = acc[3] + bo.w;
                *reinterpret_cast<float4*>(&out[(long long)ag * D_OUT + w * 16 + g * 4]) = o4;
            }
        }
    }
}

extern "C" void kernel_launch(void* const* d_in, const int* in_sizes, int n_in,
                              void* d_out, int out_size, void* d_ws, size_t ws_size,
                              hipStream_t stream) {
    const float* x        = (const float*)d_in[0];
    const float* x_lstm   = (const float*)d_in[1];
    const float* z        = (const float*)d_in[2];
    const int*   edge_idx = (const int*)d_in[3];   // [2][N_EDGES]; row = first half
    const float* edge_attr= (const float*)d_in[4];
    const int*   node_idx = (const int*)d_in[5];
    const float* W1       = (const float*)d_in[6];
    const float* b1       = (const float*)d_in[7];
    const float* W2       = (const float*)d_in[8];
    const float* b2       = (const float*)d_in[9];
    float* out = (float*)d_out;

    // ws layout (256B-aligned slots); cnt & mask contiguous for single zero
    char* wsp = (char*)d_ws;
    size_t o = 0;
    auto alloc = [&](size_t bytes) { char* p = wsp + o; o = (o + bytes + 255) & ~(size_t)255; return p; };
    int* cnt    = (int*)alloc((size_t)N_NODES * 4);                // 400,128 B slot
    int* mask   = (int*)alloc((size_t)N_NODES * 4);                // 400,128 B slot
    int* bucket = (int*)alloc((size_t)N_NODES * BCAP * 4);         // 25.6 MB
    unsigned short* w1p = (unsigned short*)alloc((size_t)16 * 7 * 64 * 8 * 2);  // 114,688 B
    unsigned short* w2p = (unsigned short*)alloc((size_t)4 * 8 * 64 * 8 * 2);   //  32,768 B

    // cooperative chain (prep + mask + place in one dispatch)
    {
        const float* W1a = W1; const float* W2a = W2;
        unsigned short* w1pa = w1p; unsigned short* w2pa = w2p;
        int4* zbase = (int4*)cnt;
        const int* nidxa = node_idx; int* maska = mask;
        const int* rowa = edge_idx; int* cnta = cnt; int* buckta = bucket;
        void* args[] = {&W1a, &W2a, &w1pa, &w2pa, &zbase,
                        &nidxa, &maska, &rowa, &cnta, &buckta};
        hipLaunchCooperativeKernel(reinterpret_cast<void*>(chain_coop),
                                   dim3(COOP_BLOCKS), dim3(256), args, 0, stream);
    }

    mlp_mfma<<<(N_AGENTS + AGB - 1) / AGB, 256, 0, stream>>>(
        x, x_lstm, z, edge_attr, cnt, bucket, node_idx, w1p, b1, w2p, b2, out);
}

// Round 17
// 99.105 us; speedup vs baseline: 2.2501x; 2.2501x over previous
//
#include <hip/hip_runtime.h>

#define N_NODES  100000
#define N_EDGES  1600000
#define N_AGENTS 50000
#define D_EDGE   48
#define D_IN     208
#define D_HID    256
#define D_OUT    64

#define K1_PAD   224            // D_IN padded to 7*32 for MFMA K-steps
#define F_STRIDE 248            // feat LDS row stride (u16)
#define H_STRIDE 264            // hbuf LDS row stride (u16)
#define AGB      64             // agents per MLP block

#define BCAP     64             // per-node bucket capacity (P(deg>64) ~ 1e-20)
#define PREP_BLOCKS 36          // 9216 threads for weight packing
#define ZERO_INT4   50016       // cnt slot + mask slot: 800,256 bytes / 16

typedef __attribute__((ext_vector_type(8))) short short8;   // 8 bf16 = 4 VGPRs
typedef __attribute__((ext_vector_type(4))) float f32x4;

static __device__ __forceinline__ unsigned short f2bf(float f) {
    unsigned u = __float_as_uint(f);
    u += 0x7FFFu + ((u >> 16) & 1u);    // round-to-nearest-even
    return (unsigned short)(u >> 16);
}

// ---------------------------------------------------------------------------
// prep0 — byte-identical to round 14.
// ---------------------------------------------------------------------------
__global__ __launch_bounds__(256)
void prep0(const float* __restrict__ W1, const float* __restrict__ W2,
           unsigned short* __restrict__ w1p, unsigned short* __restrict__ w2p,
           int4* __restrict__ zbase) {
    const int b = blockIdx.x;
    if (b < PREP_BLOCKS) {
        int t = b * 256 + threadIdx.x;
        if (t < 16 * 7 * 64) {                       // W1 fragments
            int lane = t & 63;
            int ks   = (t >> 6) % 7;
            int tile = t / (7 * 64);
            int n = tile * 16 + (lane & 15);
            int kb = ks * 32 + (lane >> 4) * 8;
            unsigned short v[8];
            #pragma unroll
            for (int j = 0; j < 8; ++j) {
                int k = kb + j;
                v[j] = (k < D_IN) ? f2bf(W1[k * D_HID + n]) : (unsigned short)0;
            }
            #pragma unroll
            for (int j = 0; j < 8; ++j) w1p[t * 8 + j] = v[j];
        } else if (t < 16 * 7 * 64 + 4 * 8 * 64) {   // W2 fragments
            int u = t - 16 * 7 * 64;
            int lane = u & 63;
            int ks   = (u >> 6) & 7;
            int tile = u / (8 * 64);
            int o = tile * 16 + (lane & 15);
            int kb = ks * 32 + (lane >> 4) * 8;
            #pragma unroll
            for (int j = 0; j < 8; ++j)
                w2p[u * 8 + j] = f2bf(W2[(kb + j) * D_OUT + o]);
        }
    } else {
        int i = (b - PREP_BLOCKS) * 256 + threadIdx.x;
        if (i < ZERO_INT4) {
            int4 zz; zz.x = 0; zz.y = 0; zz.z = 0; zz.w = 0;
            zbase[i] = zz;
        }
    }
}

// ---------------------------------------------------------------------------
// mask / place — byte-identical to round 14.
// ---------------------------------------------------------------------------
__global__ __launch_bounds__(256)
void mask_kernel(const int* __restrict__ node_idx, int* __restrict__ mask) {
    int i = blockIdx.x * 256 + threadIdx.x;
    if (i < N_AGENTS) mask[node_idx[i]] = 1;
}

__global__ __launch_bounds__(256)
void place_kernel(const int* __restrict__ row, const int* __restrict__ mask,
                  int* __restrict__ cnt, int* __restrict__ bucket) {
    int e = blockIdx.x * 256 + threadIdx.x;
    if (e >= N_EDGES) return;
    int r = row[e];
    if (!mask[r]) return;
    int pos = atomicAdd(&cnt[r], 1);
    if ((unsigned)pos < (unsigned)BCAP) bucket[r * BCAP + pos] = e;
}

// ---------------------------------------------------------------------------
// MFMA MLP with fused edge aggregation. ONLY change vs round 14: the edge
// loop processes 4 edges/iteration with int4 bucket loads -> 12 float4
// loads in flight (2x the memory-level parallelism on the latency chain).
// ---------------------------------------------------------------------------
__global__ __launch_bounds__(256)
void mlp_mfma(const float* __restrict__ x,
              const float* __restrict__ x_lstm,
              const float* __restrict__ z,
              const float* __restrict__ edge_attr,
              const int* __restrict__ cnt,
              const int* __restrict__ bucket,
              const int* __restrict__ node_idx,
              const unsigned short* __restrict__ w1p,
              const float* __restrict__ b1,
              const unsigned short* __restrict__ w2p,
              const float* __restrict__ b2,
              float* __restrict__ out) {
    __shared__ unsigned short feat[AGB][F_STRIDE];   // 31,744 B
    __shared__ unsigned short hbuf[AGB][H_STRIDE];   // 33,792 B

    const int tid  = threadIdx.x;
    const int w    = tid >> 6;
    const int lane = tid & 63;
    const int ag0  = blockIdx.x * AGB;

    // ---- gather: 4 threads/agent; x/lstm/z float4 loads + edge summation ----
    {
        const int a   = tid >> 2;
        const int sub = tid & 3;
        const int ag  = ag0 + a;
        unsigned short* frow = &feat[a][0];
        if (ag < N_AGENTS) {
            const int nid = node_idx[ag];
            #pragma unroll
            for (int i = 0; i < 4; ++i) {            // x
                int q = i * 4 + sub;
                float4 v = *reinterpret_cast<const float4*>(&x[(long long)nid * 64 + q * 4]);
                ushort4 b; b.x = f2bf(v.x); b.y = f2bf(v.y); b.z = f2bf(v.z); b.w = f2bf(v.w);
                *reinterpret_cast<ushort4*>(&frow[q * 4]) = b;
            }
            #pragma unroll
            for (int i = 0; i < 4; ++i) {            // x_lstm
                int q = i * 4 + sub;
                float4 v = *reinterpret_cast<const float4*>(&x_lstm[(long long)ag * 64 + q * 4]);
                ushort4 b; b.x = f2bf(v.x); b.y = f2bf(v.y); b.z = f2bf(v.z); b.w = f2bf(v.w);
                *reinterpret_cast<ushort4*>(&frow[64 + q * 4]) = b;
            }
            #pragma unroll
            for (int i = 0; i < 2; ++i) {            // z
                int q = i * 4 + sub;
                float4 v = *reinterpret_cast<const float4*>(&z[(long long)ag * 32 + q * 4]);
                ushort4 b; b.x = f2bf(v.x); b.y = f2bf(v.y); b.z = f2bf(v.z); b.w = f2bf(v.w);
                *reinterpret_cast<ushort4*>(&frow[128 + q * 4]) = b;
            }
            // edge aggregation: channels [sub*12, sub*12+12), 4 edges/iter
            {
                int deg = cnt[nid];
                if (deg > BCAP) deg = BCAP;
                const int* brow = &bucket[nid * BCAP];
                const float* ea = edge_attr + sub * 12;
                float acc[12];
                #pragma unroll
                for (int q = 0; q < 12; ++q) acc[q] = 0.f;
                int j = 0;
                for (; j + 4 <= deg; j += 4) {
                    int4 e4 = *reinterpret_cast<const int4*>(&brow[j]);   // 16B-aligned
                    const float* p0 = ea + (long long)e4.x * D_EDGE;
                    const float* p1 = ea + (long long)e4.y * D_EDGE;
                    const float* p2 = ea + (long long)e4.z * D_EDGE;
                    const float* p3 = ea + (long long)e4.w * D_EDGE;
                    float4 a0 = *reinterpret_cast<const float4*>(p0);
                    float4 a1 = *reinterpret_cast<const float4*>(p0 + 4);
                    float4 a2 = *reinterpret_cast<const float4*>(p0 + 8);
                    float4 b0 = *reinterpret_cast<const float4*>(p1);
                    float4 b1v = *reinterpret_cast<const float4*>(p1 + 4);
                    float4 b2v = *reinterpret_cast<const float4*>(p1 + 8);
                    float4 c0 = *reinterpret_cast<const float4*>(p2);
                    float4 c1 = *reinterpret_cast<const float4*>(p2 + 4);
                    float4 c2 = *reinterpret_cast<const float4*>(p2 + 8);
                    float4 d0 = *reinterpret_cast<const float4*>(p3);
                    float4 d1 = *reinterpret_cast<const float4*>(p3 + 4);
                    float4 d2 = *reinterpret_cast<const float4*>(p3 + 8);
                    acc[0] += a0.x + b0.x;  acc[1] += a0.y + b0.y;
                    acc[2] += a0.z + b0.z;  acc[3] += a0.w + b0.w;
                    acc[4] += a1.x + b1v.x; acc[5] += a1.y + b1v.y;
                    acc[6] += a1.z + b1v.z; acc[7] += a1.w + b1v.w;
                    acc[8] += a2.x + b2v.x; acc[9] += a2.y + b2v.y;
                    acc[10]+= a2.z + b2v.z; acc[11]+= a2.w + b2v.w;
                    acc[0] += c0.x + d0.x;  acc[1] += c0.y + d0.y;
                    acc[2] += c0.z + d0.z;  acc[3] += c0.w + d0.w;
                    acc[4] += c1.x + d1.x;  acc[5] += c1.y + d1.y;
                    acc[6] += c1.z + d1.z;  acc[7] += c1.w + d1.w;
                    acc[8] += c2.x + d2.x;  acc[9] += c2.y + d2.y;
                    acc[10]+= c2.z + d2.z;  acc[11]+= c2.w + d2.w;
                }
                for (; j < deg; ++j) {
                    const float* p0 = ea + (long long)brow[j] * D_EDGE;
                    float4 a0 = *reinterpret_cast<const float4*>(p0);
                    float4 a1 = *reinterpret_cast<const float4*>(p0 + 4);
                    float4 a2 = *reinterpret_cast<const float4*>(p0 + 8);
                    acc[0] += a0.x; acc[1] += a0.y; acc[2]  += a0.z; acc[3]  += a0.w;
                    acc[4] += a1.x; acc[5] += a1.y; acc[6]  += a1.z; acc[7]  += a1.w;
                    acc[8] += a2.x; acc[9] += a2.y; acc[10] += a2.z; acc[11] += a2.w;
                }
                ushort4 u0, u1, u2;
                u0.x = f2bf(acc[0]); u0.y = f2bf(acc[1]); u0.z = f2bf(acc[2]);  u0.w = f2bf(acc[3]);
                u1.x = f2bf(acc[4]); u1.y = f2bf(acc[5]); u1.z = f2bf(acc[6]);  u1.w = f2bf(acc[7]);
                u2.x = f2bf(acc[8]); u2.y = f2bf(acc[9]); u2.z = f2bf(acc[10]); u2.w = f2bf(acc[11]);
                *reinterpret_cast<ushort4*>(&frow[160 + sub * 12])     = u0;
                *reinterpret_cast<ushort4*>(&frow[160 + sub * 12 + 4]) = u1;
                *reinterpret_cast<ushort4*>(&frow[160 + sub * 12 + 8]) = u2;
            }
            ushort4 zz; zz.x = 0; zz.y = 0; zz.z = 0; zz.w = 0;
            *reinterpret_cast<ushort4*>(&frow[208 + sub * 4]) = zz;   // pad
        } else {
            ushort4 zz; zz.x = 0; zz.y = 0; zz.z = 0; zz.w = 0;
            #pragma unroll
            for (int i = 0; i < 14; ++i)
                *reinterpret_cast<ushort4*>(&frow[(i * 4 + sub) * 4]) = zz;
        }
    }
    __syncthreads();

    const int m16 = lane & 15;
    const int g   = lane >> 4;

    const short8* w1v = reinterpret_cast<const short8*>(w1p);
    const short8* w2v = reinterpret_cast<const short8*>(w2p);

    // ---- layer 1: 2 chunks x {2 M-tiles, 4 N-tiles x 7 K} ----
    for (int mc = 0; mc < 2; ++mc) {
        const int a0 = mc * 32 + m16;
        const int a1 = mc * 32 + 16 + m16;
        short8 bf0[7], bf1[7];
        #pragma unroll
        for (int ks = 0; ks < 7; ++ks) {
            bf0[ks] = *reinterpret_cast<const short8*>(&feat[a0][ks * 32 + g * 8]);
            bf1[ks] = *reinterpret_cast<const short8*>(&feat[a1][ks * 32 + g * 8]);
        }
        #pragma unroll
        for (int nt = 0; nt < 4; ++nt) {
            const int gt = w * 4 + nt;
            f32x4 c0 = {0.f, 0.f, 0.f, 0.f};
            f32x4 c1 = {0.f, 0.f, 0.f, 0.f};
            #pragma unroll
            for (int ks = 0; ks < 7; ++ks) {
                short8 wf = w1v[(gt * 7 + ks) * 64 + lane];
                c0 = __builtin_amdgcn_mfma_f32_16x16x32_bf16(wf, bf0[ks], c0, 0, 0, 0);
                c1 = __builtin_amdgcn_mfma_f32_16x16x32_bf16(wf, bf1[ks], c1, 0, 0, 0);
            }
            float4 bb = *reinterpret_cast<const float4*>(&b1[gt * 16 + g * 4]);
            ushort4 h0, h1;
            h0.x = f2bf(fmaxf(c0[0] + bb.x, 0.f));
            h0.y = f2bf(fmaxf(c0[1] + bb.y, 0.f));
            h0.z = f2bf(fmaxf(c0[2] + bb.z, 0.f));
            h0.w = f2bf(fmaxf(c0[3] + bb.w, 0.f));
            h1.x = f2bf(fmaxf(c1[0] + bb.x, 0.f));
            h1.y = f2bf(fmaxf(c1[1] + bb.y, 0.f));
            h1.z = f2bf(fmaxf(c1[2] + bb.z, 0.f));
            h1.w = f2bf(fmaxf(c1[3] + bb.w, 0.f));
            *reinterpret_cast<ushort4*>(&hbuf[a0][gt * 16 + g * 4]) = h0;
            *reinterpret_cast<ushort4*>(&hbuf[a1][gt * 16 + g * 4]) = h1;
        }
    }
    __syncthreads();

    // ---- layer 2: wave w owns units [w*16, w*16+16); 4 M-tiles ----
    {
        short8 w2f[8];
        #pragma unroll
        for (int ks = 0; ks < 8; ++ks)
            w2f[ks] = w2v[(w * 8 + ks) * 64 + lane];

        float4 bo = *reinterpret_cast<const float4*>(&b2[w * 16 + g * 4]);
        #pragma unroll
        for (int mt = 0; mt < 4; ++mt) {
            const int a = mt * 16 + m16;
            short8 hf[8];
            #pragma unroll
            for (int ks = 0; ks < 8; ++ks)
                hf[ks] = *reinterpret_cast<const short8*>(&hbuf[a][ks * 32 + g * 8]);
            f32x4 acc = {0.f, 0.f, 0.f, 0.f};
            #pragma unroll
            for (int ks = 0; ks < 8; ++ks)
                acc = __builtin_amdgcn_mfma_f32_16x16x32_bf16(w2f[ks], hf[ks], acc, 0, 0, 0);
            const int ag = ag0 + a;
            if (ag < N_AGENTS) {
                float4 o4;
                o4.x = acc[0] + bo.x;
                o4.y = acc[1] + bo.y;
                o4.z = acc[2] + bo.z;
                o4.w = acc[3] + bo.w;
                *reinterpret_cast<float4*>(&out[(long long)ag * D_OUT + w * 16 + g * 4]) = o4;
            }
        }
    }
}

extern "C" void kernel_launch(void* const* d_in, const int* in_sizes, int n_in,
                              void* d_out, int out_size, void* d_ws, size_t ws_size,
                              hipStream_t stream) {
    const float* x        = (const float*)d_in[0];
    const float* x_lstm   = (const float*)d_in[1];
    const float* z        = (const float*)d_in[2];
    const int*   edge_idx = (const int*)d_in[3];   // [2][N_EDGES]; row = first half
    const float* edge_attr= (const float*)d_in[4];
    const int*   node_idx = (const int*)d_in[5];
    const float* W1       = (const float*)d_in[6];
    const float* b1       = (const float*)d_in[7];
    const float* W2       = (const float*)d_in[8];
    const float* b2       = (const float*)d_in[9];
    float* out = (float*)d_out;

    // ws layout (256B-aligned slots); cnt & mask contiguous for single zero
    char* wsp = (char*)d_ws;
    size_t o = 0;
    auto alloc = [&](size_t bytes) { char* p = wsp + o; o = (o + bytes + 255) & ~(size_t)255; return p; };
    int* cnt    = (int*)alloc((size_t)N_NODES * 4);                // 400,128 B slot
    int* mask   = (int*)alloc((size_t)N_NODES * 4);                // 400,128 B slot
    int* bucket = (int*)alloc((size_t)N_NODES * BCAP * 4);         // 25.6 MB
    unsigned short* w1p = (unsigned short*)alloc((size_t)16 * 7 * 64 * 8 * 2);  // 114,688 B
    unsigned short* w2p = (unsigned short*)alloc((size_t)4 * 8 * 64 * 8 * 2);   //  32,768 B

    // prep0 zeroes [cnt, bucket) = 800,256 B = 50,016 int4  (ZERO_INT4)
    prep0<<<PREP_BLOCKS + (ZERO_INT4 + 255) / 256, 256, 0, stream>>>(
        W1, W2, w1p, w2p, (int4*)cnt);
    mask_kernel<<<(N_AGENTS + 255) / 256, 256, 0, stream>>>(node_idx, mask);
    place_kernel<<<(N_EDGES + 255) / 256, 256, 0, stream>>>(edge_idx, mask, cnt, bucket);
    mlp_mfma<<<(N_AGENTS + AGB - 1) / AGB, 256, 0, stream>>>(
        x, x_lstm, z, edge_attr, cnt, bucket, node_idx, w1p, b1, w2p, b2, out);
}

// Round 18
// 96.105 us; speedup vs baseline: 2.3203x; 1.0312x over previous
//
#include <hip/hip_runtime.h>

#define N_NODES  100000
#define N_EDGES  1600000
#define N_AGENTS 50000
#define D_EDGE   48
#define D_IN     208
#define D_HID    256
#define D_OUT    64

#define K1_PAD   224            // D_IN padded to 7*32 for MFMA K-steps
#define F_STRIDE 248            // feat LDS row stride (u16)
#define H_STRIDE 264            // hbuf LDS row stride (u16)
#define AGB      64             // agents per MLP block

#define BCAP     64             // per-node bucket capacity (P(deg>64) ~ 1e-20)
#define PACK_BLOCKS 36          // 9216 threads for weight packing
#define ZERO_INT4   25008       // cnt slot only: 400,128 bytes / 16
#define ZERO_BLOCKS 98          // ceil(25008/256)
#define STAMP_BLOCKS 196        // ceil(50000/256)
#define STAMP_MAGIC 0x5A5A0000  // r<2^17 -> stamp in [0x5A5A0000,0x5A5BFFFF]; 0xAAAAAAAA excluded

typedef __attribute__((ext_vector_type(8))) short short8;   // 8 bf16 = 4 VGPRs
typedef __attribute__((ext_vector_type(4))) float f32x4;

static __device__ __forceinline__ unsigned short f2bf(float f) {
    unsigned u = __float_as_uint(f);
    u += 0x7FFFu + ((u >> 16) & 1u);    // round-to-nearest-even
    return (unsigned short)(u >> 16);
}

// ---------------------------------------------------------------------------
// prep0: blocks [0,36) pack W1/W2; [36,134) zero cnt; [134,330) stamp mask.
// Stamp needs no zero-init (self-validating: mask[r] must equal r^MAGIC),
// so the mask phase fuses into this dispatch with NO ordering dependency.
// ---------------------------------------------------------------------------
__global__ __launch_bounds__(256)
void prep0(const float* __restrict__ W1, const float* __restrict__ W2,
           unsigned short* __restrict__ w1p, unsigned short* __restrict__ w2p,
           int4* __restrict__ zbase,
           const int* __restrict__ node_idx, int* __restrict__ mask) {
    const int b = blockIdx.x;
    if (b < PACK_BLOCKS) {
        int t = b * 256 + threadIdx.x;
        if (t < 16 * 7 * 64) {                       // W1 fragments
            int lane = t & 63;
            int ks   = (t >> 6) % 7;
            int tile = t / (7 * 64);
            int n = tile * 16 + (lane & 15);
            int kb = ks * 32 + (lane >> 4) * 8;
            unsigned short v[8];
            #pragma unroll
            for (int j = 0; j < 8; ++j) {
                int k = kb + j;
                v[j] = (k < D_IN) ? f2bf(W1[k * D_HID + n]) : (unsigned short)0;
            }
            #pragma unroll
            for (int j = 0; j < 8; ++j) w1p[t * 8 + j] = v[j];
        } else if (t < 16 * 7 * 64 + 4 * 8 * 64) {   // W2 fragments
            int u = t - 16 * 7 * 64;
            int lane = u & 63;
            int ks   = (u >> 6) & 7;
            int tile = u / (8 * 64);
            int o = tile * 16 + (lane & 15);
            int kb = ks * 32 + (lane >> 4) * 8;
            #pragma unroll
            for (int j = 0; j < 8; ++j)
                w2p[u * 8 + j] = f2bf(W2[(kb + j) * D_OUT + o]);
        }
    } else if (b < PACK_BLOCKS + ZERO_BLOCKS) {
        int i = (b - PACK_BLOCKS) * 256 + threadIdx.x;
        if (i < ZERO_INT4) {
            int4 zz; zz.x = 0; zz.y = 0; zz.z = 0; zz.w = 0;
            zbase[i] = zz;
        }
    } else {
        int i = (b - PACK_BLOCKS - ZERO_BLOCKS) * 256 + threadIdx.x;
        if (i < N_AGENTS) {
            int nid = node_idx[i];
            mask[nid] = nid ^ STAMP_MAGIC;           // self-validating stamp
        }
    }
}

// ---------------------------------------------------------------------------
// place — r14 body with stamp check instead of boolean mask.
// ---------------------------------------------------------------------------
__global__ __launch_bounds__(256)
void place_kernel(const int* __restrict__ row, const int* __restrict__ mask,
                  int* __restrict__ cnt, int* __restrict__ bucket) {
    int e = blockIdx.x * 256 + threadIdx.x;
    if (e >= N_EDGES) return;
    int r = row[e];
    if (mask[r] != (r ^ STAMP_MAGIC)) return;
    int pos = atomicAdd(&cnt[r], 1);
    if ((unsigned)pos < (unsigned)BCAP) bucket[r * BCAP + pos] = e;
}

// ---------------------------------------------------------------------------
// MFMA MLP with fused edge aggregation — byte-identical to round 17.
// ---------------------------------------------------------------------------
__global__ __launch_bounds__(256)
void mlp_mfma(const float* __restrict__ x,
              const float* __restrict__ x_lstm,
              const float* __restrict__ z,
              const float* __restrict__ edge_attr,
              const int* __restrict__ cnt,
              const int* __restrict__ bucket,
              const int* __restrict__ node_idx,
              const unsigned short* __restrict__ w1p,
              const float* __restrict__ b1,
              const unsigned short* __restrict__ w2p,
              const float* __restrict__ b2,
              float* __restrict__ out) {
    __shared__ unsigned short feat[AGB][F_STRIDE];   // 31,744 B
    __shared__ unsigned short hbuf[AGB][H_STRIDE];   // 33,792 B

    const int tid  = threadIdx.x;
    const int w    = tid >> 6;
    const int lane = tid & 63;
    const int ag0  = blockIdx.x * AGB;

    // ---- gather: 4 threads/agent; x/lstm/z float4 loads + edge summation ----
    {
        const int a   = tid >> 2;
        const int sub = tid & 3;
        const int ag  = ag0 + a;
        unsigned short* frow = &feat[a][0];
        if (ag < N_AGENTS) {
            const int nid = node_idx[ag];
            #pragma unroll
            for (int i = 0; i < 4; ++i) {            // x
                int q = i * 4 + sub;
                float4 v = *reinterpret_cast<const float4*>(&x[(long long)nid * 64 + q * 4]);
                ushort4 b; b.x = f2bf(v.x); b.y = f2bf(v.y); b.z = f2bf(v.z); b.w = f2bf(v.w);
                *reinterpret_cast<ushort4*>(&frow[q * 4]) = b;
            }
            #pragma unroll
            for (int i = 0; i < 4; ++i) {            // x_lstm
                int q = i * 4 + sub;
                float4 v = *reinterpret_cast<const float4*>(&x_lstm[(long long)ag * 64 + q * 4]);
                ushort4 b; b.x = f2bf(v.x); b.y = f2bf(v.y); b.z = f2bf(v.z); b.w = f2bf(v.w);
                *reinterpret_cast<ushort4*>(&frow[64 + q * 4]) = b;
            }
            #pragma unroll
            for (int i = 0; i < 2; ++i) {            // z
                int q = i * 4 + sub;
                float4 v = *reinterpret_cast<const float4*>(&z[(long long)ag * 32 + q * 4]);
                ushort4 b; b.x = f2bf(v.x); b.y = f2bf(v.y); b.z = f2bf(v.z); b.w = f2bf(v.w);
                *reinterpret_cast<ushort4*>(&frow[128 + q * 4]) = b;
            }
            // edge aggregation: channels [sub*12, sub*12+12), 4 edges/iter
            {
                int deg = cnt[nid];
                if (deg > BCAP) deg = BCAP;
                const int* brow = &bucket[nid * BCAP];
                const float* ea = edge_attr + sub * 12;
                float acc[12];
                #pragma unroll
                for (int q = 0; q < 12; ++q) acc[q] = 0.f;
                int j = 0;
                for (; j + 4 <= deg; j += 4) {
                    int4 e4 = *reinterpret_cast<const int4*>(&brow[j]);   // 16B-aligned
                    const float* p0 = ea + (long long)e4.x * D_EDGE;
                    const float* p1 = ea + (long long)e4.y * D_EDGE;
                    const float* p2 = ea + (long long)e4.z * D_EDGE;
                    const float* p3 = ea + (long long)e4.w * D_EDGE;
                    float4 a0 = *reinterpret_cast<const float4*>(p0);
                    float4 a1 = *reinterpret_cast<const float4*>(p0 + 4);
                    float4 a2 = *reinterpret_cast<const float4*>(p0 + 8);
                    float4 b0 = *reinterpret_cast<const float4*>(p1);
                    float4 b1v = *reinterpret_cast<const float4*>(p1 + 4);
                    float4 b2v = *reinterpret_cast<const float4*>(p1 + 8);
                    float4 c0 = *reinterpret_cast<const float4*>(p2);
                    float4 c1 = *reinterpret_cast<const float4*>(p2 + 4);
                    float4 c2 = *reinterpret_cast<const float4*>(p2 + 8);
                    float4 d0 = *reinterpret_cast<const float4*>(p3);
                    float4 d1 = *reinterpret_cast<const float4*>(p3 + 4);
                    float4 d2 = *reinterpret_cast<const float4*>(p3 + 8);
                    acc[0] += a0.x + b0.x;  acc[1] += a0.y + b0.y;
                    acc[2] += a0.z + b0.z;  acc[3] += a0.w + b0.w;
                    acc[4] += a1.x + b1v.x; acc[5] += a1.y + b1v.y;
                    acc[6] += a1.z + b1v.z; acc[7] += a1.w + b1v.w;
                    acc[8] += a2.x + b2v.x; acc[9] += a2.y + b2v.y;
                    acc[10]+= a2.z + b2v.z; acc[11]+= a2.w + b2v.w;
                    acc[0] += c0.x + d0.x;  acc[1] += c0.y + d0.y;
                    acc[2] += c0.z + d0.z;  acc[3] += c0.w + d0.w;
                    acc[4] += c1.x + d1.x;  acc[5] += c1.y + d1.y;
                    acc[6] += c1.z + d1.z;  acc[7] += c1.w + d1.w;
                    acc[8] += c2.x + d2.x;  acc[9] += c2.y + d2.y;
                    acc[10]+= c2.z + d2.z;  acc[11]+= c2.w + d2.w;
                }
                for (; j < deg; ++j) {
                    const float* p0 = ea + (long long)brow[j] * D_EDGE;
                    float4 a0 = *reinterpret_cast<const float4*>(p0);
                    float4 a1 = *reinterpret_cast<const float4*>(p0 + 4);
                    float4 a2 = *reinterpret_cast<const float4*>(p0 + 8);
                    acc[0] += a0.x; acc[1] += a0.y; acc[2]  += a0.z; acc[3]  += a0.w;
                    acc[4] += a1.x; acc[5] += a1.y; acc[6]  += a1.z; acc[7]  += a1.w;
                    acc[8] += a2.x; acc[9] += a2.y; acc[10] += a2.z; acc[11] += a2.w;
                }
                ushort4 u0, u1, u2;
                u0.x = f2bf(acc[0]); u0.y = f2bf(acc[1]); u0.z = f2bf(acc[2]);  u0.w = f2bf(acc[3]);
                u1.x = f2bf(acc[4]); u1.y = f2bf(acc[5]); u1.z = f2bf(acc[6]);  u1.w = f2bf(acc[7]);
                u2.x = f2bf(acc[8]); u2.y = f2bf(acc[9]); u2.z = f2bf(acc[10]); u2.w = f2bf(acc[11]);
                *reinterpret_cast<ushort4*>(&frow[160 + sub * 12])     = u0;
                *reinterpret_cast<ushort4*>(&frow[160 + sub * 12 + 4]) = u1;
                *reinterpret_cast<ushort4*>(&frow[160 + sub * 12 + 8]) = u2;
            }
            ushort4 zz; zz.x = 0; zz.y = 0; zz.z = 0; zz.w = 0;
            *reinterpret_cast<ushort4*>(&frow[208 + sub * 4]) = zz;   // pad
        } else {
            ushort4 zz; zz.x = 0; zz.y = 0; zz.z = 0; zz.w = 0;
            #pragma unroll
            for (int i = 0; i < 14; ++i)
                *reinterpret_cast<ushort4*>(&frow[(i * 4 + sub) * 4]) = zz;
        }
    }
    __syncthreads();

    const int m16 = lane & 15;
    const int g   = lane >> 4;

    const short8* w1v = reinterpret_cast<const short8*>(w1p);
    const short8* w2v = reinterpret_cast<const short8*>(w2p);

    // ---- layer 1: 2 chunks x {2 M-tiles, 4 N-tiles x 7 K} ----
    for (int mc = 0; mc < 2; ++mc) {
        const int a0 = mc * 32 + m16;
        const int a1 = mc * 32 + 16 + m16;
        short8 bf0[7], bf1[7];
        #pragma unroll
        for (int ks = 0; ks < 7; ++ks) {
            bf0[ks] = *reinterpret_cast<const short8*>(&feat[a0][ks * 32 + g * 8]);
            bf1[ks] = *reinterpret_cast<const short8*>(&feat[a1][ks * 32 + g * 8]);
        }
        #pragma unroll
        for (int nt = 0; nt < 4; ++nt) {
            const int gt = w * 4 + nt;
            f32x4 c0 = {0.f, 0.f, 0.f, 0.f};
            f32x4 c1 = {0.f, 0.f, 0.f, 0.f};
            #pragma unroll
            for (int ks = 0; ks < 7; ++ks) {
                short8 wf = w1v[(gt * 7 + ks) * 64 + lane];
                c0 = __builtin_amdgcn_mfma_f32_16x16x32_bf16(wf, bf0[ks], c0, 0, 0, 0);
                c1 = __builtin_amdgcn_mfma_f32_16x16x32_bf16(wf, bf1[ks], c1, 0, 0, 0);
            }
            float4 bb = *reinterpret_cast<const float4*>(&b1[gt * 16 + g * 4]);
            ushort4 h0, h1;
            h0.x = f2bf(fmaxf(c0[0] + bb.x, 0.f));
            h0.y = f2bf(fmaxf(c0[1] + bb.y, 0.f));
            h0.z = f2bf(fmaxf(c0[2] + bb.z, 0.f));
            h0.w = f2bf(fmaxf(c0[3] + bb.w, 0.f));
            h1.x = f2bf(fmaxf(c1[0] + bb.x, 0.f));
            h1.y = f2bf(fmaxf(c1[1] + bb.y, 0.f));
            h1.z = f2bf(fmaxf(c1[2] + bb.z, 0.f));
            h1.w = f2bf(fmaxf(c1[3] + bb.w, 0.f));
            *reinterpret_cast<ushort4*>(&hbuf[a0][gt * 16 + g * 4]) = h0;
            *reinterpret_cast<ushort4*>(&hbuf[a1][gt * 16 + g * 4]) = h1;
        }
    }
    __syncthreads();

    // ---- layer 2: wave w owns units [w*16, w*16+16); 4 M-tiles ----
    {
        short8 w2f[8];
        #pragma unroll
        for (int ks = 0; ks < 8; ++ks)
            w2f[ks] = w2v[(w * 8 + ks) * 64 + lane];

        float4 bo = *reinterpret_cast<const float4*>(&b2[w * 16 + g * 4]);
        #pragma unroll
        for (int mt = 0; mt < 4; ++mt) {
            const int a = mt * 16 + m16;
            short8 hf[8];
            #pragma unroll
            for (int ks = 0; ks < 8; ++ks)
                hf[ks] = *reinterpret_cast<const short8*>(&hbuf[a][ks * 32 + g * 8]);
            f32x4 acc = {0.f, 0.f, 0.f, 0.f};
            #pragma unroll
            for (int ks = 0; ks < 8; ++ks)
                acc = __builtin_amdgcn_mfma_f32_16x16x32_bf16(w2f[ks], hf[ks], acc, 0, 0, 0);
            const int ag = ag0 + a;
            if (ag < N_AGENTS) {
                float4 o4;
                o4.x = acc[0] + bo.x;
                o4.y = acc[1] + bo.y;
                o4.z = acc[2] + bo.z;
                o4.w = acc[3] + bo.w;
                *reinterpret_cast<float4*>(&out[(long long)ag * D_OUT + w * 16 + g * 4]) = o4;
            }
        }
    }
}

extern "C" void kernel_launch(void* const* d_in, const int* in_sizes, int n_in,
                              void* d_out, int out_size, void* d_ws, size_t ws_size,
                              hipStream_t stream) {
    const float* x        = (const float*)d_in[0];
    const float* x_lstm   = (const float*)d_in[1];
    const float* z        = (const float*)d_in[2];
    const int*   edge_idx = (const int*)d_in[3];   // [2][N_EDGES]; row = first half
    const float* edge_attr= (const float*)d_in[4];
    const int*   node_idx = (const int*)d_in[5];
    const float* W1       = (const float*)d_in[6];
    const float* b1       = (const float*)d_in[7];
    const float* W2       = (const float*)d_in[8];
    const float* b2       = (const float*)d_in[9];
    float* out = (float*)d_out;

    // ws layout (256B-aligned slots)
    char* wsp = (char*)d_ws;
    size_t o = 0;
    auto alloc = [&](size_t bytes) { char* p = wsp + o; o = (o + bytes + 255) & ~(size_t)255; return p; };
    int* cnt    = (int*)alloc((size_t)N_NODES * 4);                // 400,128 B slot
    int* mask   = (int*)alloc((size_t)N_NODES * 4);                // stamp array (no init needed)
    int* bucket = (int*)alloc((size_t)N_NODES * BCAP * 4);         // 25.6 MB
    unsigned short* w1p = (unsigned short*)alloc((size_t)16 * 7 * 64 * 8 * 2);  // 114,688 B
    unsigned short* w2p = (unsigned short*)alloc((size_t)4 * 8 * 64 * 8 * 2);   //  32,768 B

    prep0<<<PACK_BLOCKS + ZERO_BLOCKS + STAMP_BLOCKS, 256, 0, stream>>>(
        W1, W2, w1p, w2p, (int4*)cnt, node_idx, mask);
    place_kernel<<<(N_EDGES + 255) / 256, 256, 0, stream>>>(edge_idx, mask, cnt, bucket);
    mlp_mfma<<<(N_AGENTS + AGB - 1) / AGB, 256, 0, stream>>>(
        x, x_lstm, z, edge_attr, cnt, bucket, node_idx, w1p, b1, w2p, b2, out);
}